// Round 8
// baseline (1439.647 us; speedup 1.0000x reference)
//
#include <hip/hip_runtime.h>
#include <stdint.h>

// ===================== types & helpers =====================
typedef unsigned short u16;
typedef __bf16 bf16x8 __attribute__((ext_vector_type(8)));
typedef float f32x4 __attribute__((ext_vector_type(4)));

enum { EPI_TMP = 0, EPI_BN = 1, EPI_N2D = 2, EPI_OUT = 3, EPI_BNPRELU = 4 };

__device__ __forceinline__ u16 f2bf(float x) {
  unsigned int u = __float_as_uint(x);
  u += 0x7FFFu + ((u >> 16) & 1u);           // RNE
  return (u16)(u >> 16);
}
__device__ __forceinline__ float bf2f(u16 b) {
  return __uint_as_float(((unsigned int)b) << 16);
}
__device__ __forceinline__ float bflo(unsigned int u) { return __uint_as_float(u << 16); }
__device__ __forceinline__ float bfhi(unsigned int u) { return __uint_as_float(u & 0xFFFF0000u); }
__device__ __forceinline__ ushort4 pack4(float a, float b, float c, float d) {
  return make_ushort4(f2bf(a), f2bf(b), f2bf(c), f2bf(d));
}

struct F4 { float x, y, z, w; };
__device__ __forceinline__ F4 ld4(const float* p) {
  float4 v = *(const float4*)p;
  return {v.x, v.y, v.z, v.w};
}

typedef const void __attribute__((address_space(1))) as1cv;
typedef void __attribute__((address_space(3))) as3v;
__device__ __forceinline__ void gld16(const void* g, void* l) {
  __builtin_amdgcn_global_load_lds((as1cv*)g, (as3v*)l, 16, 0, 0);
}

// ===================== preprocessing kernels =====================

__global__ void k_detect(const unsigned int* __restrict__ m, int nwords, int* __restrict__ flag) {
  int viol = 0;
  for (int i = blockIdx.x * blockDim.x + threadIdx.x; i < nwords; i += gridDim.x * blockDim.x) {
    unsigned int u = m[i];
    if (u > 1u) viol |= 1;
    if (u != 0u && u != 0x3F800000u) viol |= 2;
  }
  if (viol) atomicOr(flag, viol);
}

__global__ void k_norm(const void* __restrict__ raw, const int* __restrict__ flag,
                       unsigned char* __restrict__ mout, int N) {
  int f = *flag;
  for (int v = blockIdx.x * blockDim.x + threadIdx.x; v < N; v += gridDim.x * blockDim.x) {
    unsigned char b;
    if ((f & 1) == 0)       b = (unsigned char)(((const int*)raw)[v] != 0);
    else if ((f & 2) == 0)  b = (unsigned char)(((const float*)raw)[v] != 0.0f);
    else                    b = (unsigned char)(((const unsigned char*)raw)[v] != 0);
    mout[v] = b;
  }
}

__global__ void k_count(const int* __restrict__ ei, int E, int* __restrict__ deg) {
  for (int e = blockIdx.x * blockDim.x + threadIdx.x; e < E; e += gridDim.x * blockDim.x)
    atomicAdd(&deg[ei[E + e]], 1);
}

__global__ __launch_bounds__(1024)
void k_scanA(const int* __restrict__ deg, int* __restrict__ out,
             int* __restrict__ bsum, int n) {
  __shared__ int lws[17];
  const int tid = threadIdx.x, lane = tid & 63, wv = tid >> 6;
  const int i = blockIdx.x * 1024 + tid;
  const int v = (i < n) ? deg[i] : 0;
  int x = v;
#pragma unroll
  for (int d = 1; d < 64; d <<= 1) {
    int y = __shfl_up(x, d, 64);
    if (lane >= d) x += y;
  }
  if (lane == 63) lws[wv] = x;
  __syncthreads();
  if (tid == 0) {
    int run = 0;
#pragma unroll
    for (int k = 0; k < 16; ++k) { int t = lws[k]; lws[k] = run; run += t; }
    lws[16] = run;
  }
  __syncthreads();
  if (i < n) out[i] = x - v + lws[wv];
  if (tid == 0) bsum[blockIdx.x] = lws[16];
}

__global__ void k_scanB(int* __restrict__ bsum, int* __restrict__ offN, int nc) {
  const int t = threadIdx.x;          // 64 threads
  const int v = (t < nc) ? bsum[t] : 0;
  int x = v;
#pragma unroll
  for (int d = 1; d < 64; d <<= 1) {
    int y = __shfl_up(x, d, 64);
    if (t >= d) x += y;
  }
  if (t < nc) bsum[t] = x - v;
  if (t == nc - 1) *offN = x;
}

__global__ void k_scanC(int* __restrict__ off_, const int* __restrict__ bsum, int n) {
  int i = blockIdx.x * blockDim.x + threadIdx.x;
  if (i < n) off_[i] += bsum[i >> 10];
}

__global__ void k_fill(const int* __restrict__ ei, const int* __restrict__ ea, int E,
                       int* __restrict__ cur, int* __restrict__ elist) {
  for (int e = blockIdx.x * blockDim.x + threadIdx.x; e < E; e += gridDim.x * blockDim.x) {
    int s = ei[e];
    int d = ei[E + e];
    int a0 = ea[2 * e], a1 = ea[2 * e + 1];
    int pos = atomicAdd(&cur[d], 1);
    elist[pos] = s | (a0 << 20) | (a1 << 23);
  }
}

__global__ void k_counts(const int* __restrict__ off_, const int* __restrict__ elist,
                         unsigned char* __restrict__ cnts, int N) {
  int v = blockIdx.x * blockDim.x + threadIdx.x;
  if (v >= N) return;
  int c0=0,c1=0,c2=0,c3=0,c4=0,c5=0,d0=0,d1=0,d2=0;
  const int e1 = off_[v + 1];
  for (int e = off_[v]; e < e1; ++e) {
    int p = elist[e];
    int a = (p >> 20) & 7, b = (p >> 23) & 3;
    c0 += (a==0); c1 += (a==1); c2 += (a==2);
    c3 += (a==3); c4 += (a==4); c5 += (a==5);
    d0 += (b==0); d1 += (b==1); d2 += (b==2);
  }
  unsigned char* cp = cnts + v * 12;
  cp[0]=(unsigned char)c0; cp[1]=(unsigned char)c1; cp[2]=(unsigned char)c2;
  cp[3]=(unsigned char)c3; cp[4]=(unsigned char)c4; cp[5]=(unsigned char)c5;
  cp[6]=(unsigned char)d0; cp[7]=(unsigned char)d1; cp[8]=(unsigned char)d2;
}

// edge-emb tables -> padded [6 slots][9 rows][512], zeros in pad cols
__global__ void k_tab(const float* __restrict__ ee1, const float* __restrict__ ee2,
                      const float* __restrict__ de1, const float* __restrict__ de2,
                      float* __restrict__ tab) {
  int idx = blockIdx.x * blockDim.x + threadIdx.x;
  if (idx >= 54 * 512) return;
  int col = idx & 511, row = (idx >> 9) % 9, l = idx / (9 * 512);
  float v = 0.f;
  if (col < 500) {
    if (l < 5) v = (row < 6) ? ee1[((size_t)l * 6 + row) * 500 + col]
                             : ee2[((size_t)l * 3 + (row - 6)) * 500 + col];
    else       v = (row < 6) ? de1[(size_t)row * 500 + col]
                             : de2[(size_t)(row - 6) * 500 + col];
  }
  tab[idx] = v;
}

// weights: fp32 [L][K][Nsrc] -> bf16 transposed+padded [L][Npad][Kpad]
__global__ void k_conv_w(const float* __restrict__ src, u16* __restrict__ dst,
                         int K, int Nsrc, int Kpad, int Npad, int L) {
  size_t total = (size_t)L * Npad * Kpad;
  for (size_t idx = blockIdx.x * (size_t)blockDim.x + threadIdx.x; idx < total;
       idx += (size_t)gridDim.x * blockDim.x) {
    int k = (int)(idx % (size_t)Kpad);
    size_t r = idx / (size_t)Kpad;
    int n = (int)(r % (size_t)Npad);
    int l = (int)(r / (size_t)Npad);
    float v = 0.0f;
    if (k < K && n < Nsrc) v = src[((size_t)l * K + k) * Nsrc + n];
    dst[idx] = f2bf(v);
  }
}

// h stride = 512 u16 (1KB aligned rows); pad cols zeroed
__global__ void k_init_h(const int* __restrict__ x, const float* __restrict__ e1,
                         const float* __restrict__ e2, u16* __restrict__ h, int nReal) {
  int total = nReal * 128;
  for (int i = blockIdx.x * blockDim.x + threadIdx.x; i < total; i += gridDim.x * blockDim.x) {
    int v = i >> 7, q = i & 127, j = q << 2;
    u16* hp = h + ((size_t)v << 9) + j;
    if (j < 500) {
      int a = x[2 * v], c = x[2 * v + 1];
      F4 va = ld4(e1 + (size_t)a * 500 + j);
      F4 vc = ld4(e2 + (size_t)c * 500 + j);
      *(ushort4*)hp = pack4(va.x + vc.x, va.y + vc.y, va.z + vc.z, va.w + vc.w);
    } else {
      *(ushort4*)hp = make_ushort4(0, 0, 0, 0);
    }
  }
}

// ===================== aggregation: 2 nodes/wave, dual-stream gather pipeline =====================
__device__ __forceinline__ void add8(float* s, uint4 u) {
  s[0] += bflo(u.x); s[1] += bfhi(u.x);
  s[2] += bflo(u.y); s[3] += bfhi(u.y);
  s[4] += bflo(u.z); s[5] += bfhi(u.z);
  s[6] += bflo(u.w); s[7] += bfhi(u.w);
}

__global__ __launch_bounds__(256)
void k_aggregate(const u16* __restrict__ h, const int* __restrict__ off_,
                 const int* __restrict__ elist, const unsigned char* __restrict__ cnts,
                 const float* __restrict__ tab, u16* __restrict__ agg, int nReal) {
  const int lane = threadIdx.x & 63, wv = threadIdx.x >> 6;
  const int v0 = (blockIdx.x << 3) | (wv << 1);   // 8 nodes/block, 2 per wave
  if (v0 >= nReal) return;
  const int v1 = v0 + 1;
  const bool has1 = (v1 < nReal);
  const int j = lane << 3;                        // 8 bf16 per lane; pad cols are zero

  float s0[8], s1[8];
  {
    uint4 u = *(const uint4*)(h + ((size_t)v0 << 9) + j);   // self loop v0
    s0[0]=bflo(u.x); s0[1]=bfhi(u.x); s0[2]=bflo(u.y); s0[3]=bfhi(u.y);
    s0[4]=bflo(u.z); s0[5]=bfhi(u.z); s0[6]=bflo(u.w); s0[7]=bfhi(u.w);
  }
  if (has1) {
    uint4 u = *(const uint4*)(h + ((size_t)v1 << 9) + j);   // self loop v1
    s1[0]=bflo(u.x); s1[1]=bfhi(u.x); s1[2]=bflo(u.y); s1[3]=bfhi(u.y);
    s1[4]=bflo(u.z); s1[5]=bfhi(u.z); s1[6]=bflo(u.w); s1[7]=bfhi(u.w);
  } else {
#pragma unroll
    for (int k = 0; k < 8; ++k) s1[k] = 0.f;
  }

  int e0 = off_[v0];
  const int E0 = off_[v0 + 1];
  int e1 = E0;                                    // CSR: off_[v1] == off_[v0+1]
  const int E1 = has1 ? off_[v1 + 1] : E0;

  // joint dual-stream: 2+2 independent gathers per iteration
  while (e0 + 2 <= E0 && e1 + 2 <= E1) {
    const int pa = elist[e0]     & 0xFFFFF, pb = elist[e0 + 1] & 0xFFFFF;
    const int pc = elist[e1]     & 0xFFFFF, pd = elist[e1 + 1] & 0xFFFFF;
    uint4 ua = *(const uint4*)(h + ((size_t)pa << 9) + j);
    uint4 ub = *(const uint4*)(h + ((size_t)pb << 9) + j);
    uint4 uc = *(const uint4*)(h + ((size_t)pc << 9) + j);
    uint4 ud = *(const uint4*)(h + ((size_t)pd << 9) + j);
    add8(s0, ua); add8(s0, ub); add8(s1, uc); add8(s1, ud);
    e0 += 2; e1 += 2;
  }
  // stream-0 drain
  for (; e0 + 4 <= E0; e0 += 4) {
    uint4 a = *(const uint4*)(h + ((size_t)(elist[e0]     & 0xFFFFF) << 9) + j);
    uint4 b = *(const uint4*)(h + ((size_t)(elist[e0 + 1] & 0xFFFFF) << 9) + j);
    uint4 c = *(const uint4*)(h + ((size_t)(elist[e0 + 2] & 0xFFFFF) << 9) + j);
    uint4 d = *(const uint4*)(h + ((size_t)(elist[e0 + 3] & 0xFFFFF) << 9) + j);
    add8(s0, a); add8(s0, b); add8(s0, c); add8(s0, d);
  }
  for (; e0 < E0; ++e0) {
    uint4 u = *(const uint4*)(h + ((size_t)(elist[e0] & 0xFFFFF) << 9) + j);
    add8(s0, u);
  }
  // stream-1 drain
  for (; e1 + 4 <= E1; e1 += 4) {
    uint4 a = *(const uint4*)(h + ((size_t)(elist[e1]     & 0xFFFFF) << 9) + j);
    uint4 b = *(const uint4*)(h + ((size_t)(elist[e1 + 1] & 0xFFFFF) << 9) + j);
    uint4 c = *(const uint4*)(h + ((size_t)(elist[e1 + 2] & 0xFFFFF) << 9) + j);
    uint4 d = *(const uint4*)(h + ((size_t)(elist[e1 + 3] & 0xFFFFF) << 9) + j);
    add8(s1, a); add8(s1, b); add8(s1, c); add8(s1, d);
  }
  for (; e1 < E1; ++e1) {
    uint4 u = *(const uint4*)(h + ((size_t)(elist[e1] & 0xFFFFF) << 9) + j);
    add8(s1, u);
  }

  // hoisted edge-emb: counts x table rows (+1 on t1[4], t2[0] for self loop);
  // tab loads shared between the two nodes
  const unsigned char* cp0 = cnts + (size_t)v0 * 12;
  const unsigned char* cp1 = cnts + (size_t)(has1 ? v1 : v0) * 12;
  constexpr float ex[9] = {0.f,0.f,0.f,0.f,1.f,0.f, 1.f,0.f,0.f};
#pragma unroll
  for (int k = 0; k < 9; ++k) {
    const float c0 = (float)cp0[k] + ex[k];
    const float c1 = has1 ? ((float)cp1[k] + ex[k]) : 0.f;
    F4 t0 = ld4(tab + (k << 9) + j);
    F4 t1 = ld4(tab + (k << 9) + j + 4);
    s0[0] += c0 * t0.x; s0[1] += c0 * t0.y; s0[2] += c0 * t0.z; s0[3] += c0 * t0.w;
    s0[4] += c0 * t1.x; s0[5] += c0 * t1.y; s0[6] += c0 * t1.z; s0[7] += c0 * t1.w;
    s1[0] += c1 * t0.x; s1[1] += c1 * t0.y; s1[2] += c1 * t0.z; s1[3] += c1 * t0.w;
    s1[4] += c1 * t1.x; s1[5] += c1 * t1.y; s1[6] += c1 * t1.z; s1[7] += c1 * t1.w;
  }
  auto pk = [](float a, float b) {
    return (unsigned int)f2bf(a) | ((unsigned int)f2bf(b) << 16);
  };
  uint4 o0 = {pk(s0[0], s0[1]), pk(s0[2], s0[3]), pk(s0[4], s0[5]), pk(s0[6], s0[7])};
  *(uint4*)(agg + ((size_t)v0 << 9) + j) = o0;
  if (has1) {
    uint4 o1 = {pk(s1[0], s1[1]), pk(s1[2], s1[3]), pk(s1[4], s1[5]), pk(s1[6], s1[7])};
    *(uint4*)(agg + ((size_t)v1 << 9) + j) = o1;
  }
}

// ===================== GEMM: m97 structure (128x128, BK=64, 3 blocks/CU) + LDS-staged epilogue ======
// PROVEN R6 config (1377us, absmax 0.0098). Do not touch the sync structure.
struct EpiParams {
  const float* bias;
  const float* mean; const float* var; const float* gamma; const float* beta;
  const unsigned char* mask;
  const float* pa;
  float* outF;
  u16* outH;
  int ldOut, nReal, mReal, relu;
};

#define EPI_STRIDE 136   // u16; 272B rows, 16B-aligned

template<int EPI>
__global__ __launch_bounds__(256, 3)
void k_gemm(const u16* __restrict__ A, const u16* __restrict__ B,
            int ldA, int Kpad, int Ntiles, int NWG, EpiParams P) {
  // mainloop: sA = smem[0..8192), sB = smem[8192..16384)  (32KB)
  // epilogue: u16 tile 128 x EPI_STRIDE = 34816B  (or f32 64x132 two-pass)
  __shared__ __align__(16) u16 smem[128 * EPI_STRIDE];

  const int tid = threadIdx.x;
  const int w = tid >> 6, lane = tid & 63;
  // bijective XCD swizzle: consecutive wgs (same A-panel) cluster per XCD L2
  const int q = NWG >> 3, r = NWG & 7;
  const int xcd = blockIdx.x & 7, ii = blockIdx.x >> 3;
  const int wg = (xcd < r ? xcd * (q + 1) : r * (q + 1) + (xcd - r) * q) + ii;
  const int mt = wg / Ntiles, nt = wg % Ntiles;
  const int wm = w >> 1, wn = w & 1;          // 2x2 waves, wave tile 64x64

  f32x4 acc[4][4] = {};
  const size_t arow = (size_t)mt * 128, brow = (size_t)nt * 128;
  const int Ksteps = Kpad >> 6;

  for (int ks = 0; ks < Ksteps; ++ks) {
    const int kb = ks << 6;
#pragma unroll
    for (int it = 0; it < 4; ++it) {
      const int idx = (it << 8) | tid;
      const int row = idx >> 3, s = idx & 7;
      const int col = kb + ((s ^ (row & 7)) << 3);   // inverse-swizzled SOURCE col
      u16* dst = smem + (((it << 8) | (w << 6)) << 3);  // wave-uniform LDS base
      gld16(A + (arow + row) * (size_t)ldA + col, dst);
      gld16(B + (brow + row) * (size_t)Kpad + col, dst + 8192);
    }
    asm volatile("s_waitcnt vmcnt(0)" ::: "memory");
    __syncthreads();

#pragma unroll
    for (int kk = 0; kk < 2; ++kk) {
      const int ko8 = (kk << 2) | (lane >> 4);
      const int sw = (ko8 ^ (lane & 7)) << 3;        // swizzled read
      bf16x8 af[4], bfr[4];
#pragma unroll
      for (int m = 0; m < 4; ++m)
        af[m] = *(const bf16x8*)(smem + ((((wm << 6) | (m << 4) | (lane & 15))) << 6) + sw);
#pragma unroll
      for (int n = 0; n < 4; ++n)
        bfr[n] = *(const bf16x8*)(smem + 8192 + ((((wn << 6) | (n << 4) | (lane & 15))) << 6) + sw);
#pragma unroll
      for (int m = 0; m < 4; ++m)
#pragma unroll
        for (int n = 0; n < 4; ++n)
          acc[m][n] = __builtin_amdgcn_mfma_f32_16x16x32_bf16(af[m], bfr[n], acc[m][n], 0, 0, 0);
    }
    __syncthreads();
  }

  // ---- epilogue; C/D map: col = lane&15, row = (lane>>4)*4 + reg ----
  const int rb0 = mt * 128, cb0 = nt * 128;
  const int rloc = (wm << 6) | ((lane >> 4) << 2);   // + (m<<4) + r
  const int cloc = (wn << 6) | (lane & 15);          // + (n<<4)

  if constexpr (EPI != EPI_OUT) {
    float alpha = 0.f;
    if constexpr (EPI == EPI_BNPRELU) alpha = *P.pa;
    // per-element math in-register -> bf16 tile in LDS -> coalesced uint4 stores
#pragma unroll
    for (int n = 0; n < 4; ++n) {
      const int col = cloc + (n << 4);
      const int colg = cb0 + col;
      const bool cok = colg < P.nReal;
      float bias = 0.f, bnS = 0.f, bnB = 0.f;
      if constexpr (EPI == EPI_TMP) {
        if (cok) bias = P.bias[colg];
      }
      if constexpr (EPI == EPI_BN || EPI == EPI_BNPRELU) {
        if (cok) {
          bias = P.bias[colg];
          bnS = rsqrtf(P.var[colg] + 1e-5f) * P.gamma[colg];
          bnB = P.beta[colg] - P.mean[colg] * bnS;
        }
      }
#pragma unroll
      for (int m = 0; m < 4; ++m) {
#pragma unroll
        for (int rr = 0; rr < 4; ++rr) {
          const int row = rloc + (m << 4) + rr;
          float z = acc[m][n][rr];
          if constexpr (EPI == EPI_TMP) {
            z = fmaxf(z + bias, 0.f);
          } else if constexpr (EPI == EPI_BN) {
            z = (z + bias) * bnS + bnB;
            if (P.relu) z = fmaxf(z, 0.f);
          } else if constexpr (EPI == EPI_BNPRELU) {
            z = (z + bias) * bnS + bnB;
            z = z >= 0.f ? z : alpha * z;
          } else {  // EPI_N2D
            const int rowg = rb0 + row;
            if (rowg < P.mReal && P.mask[rowg]) z = 0.f;
          }
          smem[row * EPI_STRIDE + col] = f2bf(z);
        }
      }
    }
    __syncthreads();
#pragma unroll
    for (int it = 0; it < 8; ++it) {
      const int idx = (it << 8) | tid;
      const int row = idx >> 4, c8 = idx & 15;
      uint4 vv = *(const uint4*)(smem + row * EPI_STRIDE + (c8 << 3));
      *(uint4*)(P.outH + (size_t)(rb0 + row) * P.ldOut + cb0 + (c8 << 3)) = vv;
    }
  } else {
    // f32 output, ld=119 exact: two-pass LDS stage + flat contiguous stores
    float* sf = (float*)smem;                        // 64 x 132 f32 = 33792B
#pragma unroll
    for (int p = 0; p < 2; ++p) {
      __syncthreads();
      if (wm == p) {
#pragma unroll
        for (int n = 0; n < 4; ++n) {
          const int col = cloc + (n << 4);
          const float bias = (cb0 + col < P.nReal) ? P.bias[cb0 + col] : 0.f;
#pragma unroll
          for (int m = 0; m < 4; ++m)
#pragma unroll
            for (int rr = 0; rr < 4; ++rr) {
              const int lrow = ((lane >> 4) << 2) + (m << 4) + rr;   // 0..63
              sf[lrow * 132 + col] = acc[m][n][rr] + bias;
            }
        }
      }
      __syncthreads();
      const size_t flat0 = (size_t)(rb0 + (p << 6)) * 119;
      const size_t flatEnd = (size_t)P.mReal * 119;
#pragma unroll 2
      for (int it = 0; it < 30; ++it) {
        const int fidx = it * 256 + tid;
        if (fidx < 64 * 119) {
          const int row = fidx / 119;
          const int col = fidx - row * 119;
          const size_t g = flat0 + fidx;
          if (g < flatEnd) P.outF[g] = sf[row * 132 + col];
        }
      }
    }
  }
}

__global__ void k_fail(float* out, int n, float val) {
  for (int i = blockIdx.x * blockDim.x + threadIdx.x; i < n; i += gridDim.x * blockDim.x)
    out[i] = (i == 0) ? val : 0.f;
}

// ===================== host side =====================
static inline size_t alup(size_t x) { return (x + 255) & ~(size_t)255; }

extern "C" void kernel_launch(void* const* d_in, const int* in_sizes, int n_in,
                              void* d_out, int out_size, void* d_ws, size_t ws_size,
                              hipStream_t stream) {
  (void)n_in;
  const int N = in_sizes[0] / 2;
  const int E = in_sizes[1] / 2;
  const int Mpad = (N + 127) / 128 * 128;
  const int MT = Mpad / 128;

  // ---- plan ----
  size_t off = 0;
  auto plan = [&](size_t b) -> size_t { size_t p = off; off += alup(b); return p; };
  const size_t o_h    = plan((size_t)Mpad * 512 * 2);
  const size_t o_agg  = plan((size_t)Mpad * 512 * 2);
  const size_t o_tmp  = plan((size_t)Mpad * 1024 * 2);
  const size_t o_w1   = plan(5ull * 1024 * 512 * 2);
  const size_t o_w2   = plan(5ull * 512 * 1024 * 2);
  const size_t o_nd   = plan(512ull * 512 * 2);
  const size_t o_d1   = plan(1024ull * 512 * 2);
  const size_t o_d2   = plan(128ull * 1024 * 2);
  const size_t o_tab  = plan(54ull * 512 * 4);
  const size_t o_offv = plan((size_t)(N + 1) * 4);
  const size_t o_cur  = plan((size_t)N * 4);
  const size_t o_el   = plan((size_t)E * 4);
  const size_t o_mask = plan((size_t)N);
  const size_t o_cnt  = plan((size_t)N * 12);
  const size_t o_bsum = plan(1024);
  const size_t o_flag = plan(256);
  const size_t need = off;

  if (ws_size < need) {
    k_fail<<<1024, 256, 0, stream>>>((float*)d_out, out_size, -(float)(ws_size >> 20));
    return;
  }

  char* ws = (char*)d_ws;
  u16* h     = (u16*)(ws + o_h);
  u16* agg   = (u16*)(ws + o_agg);
  u16* tmp   = (u16*)(ws + o_tmp);
  u16* w1H   = (u16*)(ws + o_w1);
  u16* w2H   = (u16*)(ws + o_w2);
  u16* ndH   = (u16*)(ws + o_nd);
  u16* d1H   = (u16*)(ws + o_d1);
  u16* d2H   = (u16*)(ws + o_d2);
  float* tab = (float*)(ws + o_tab);
  int* offv  = (int*)(ws + o_offv);
  int* cur   = (int*)(ws + o_cur);
  int* elist = (int*)(ws + o_el);
  unsigned char* mask = (unsigned char*)(ws + o_mask);
  unsigned char* cnts = (unsigned char*)(ws + o_cnt);
  int* bsum  = (int*)(ws + o_bsum);
  int* flag  = (int*)(ws + o_flag);

  const int* x   = (const int*)d_in[0];
  const int* ei  = (const int*)d_in[1];
  const int* ea  = (const int*)d_in[2];
  const void* mraw = d_in[3];
  const float* ae1 = (const float*)d_in[4];
  const float* ae2 = (const float*)d_in[5];
  const float* ee1 = (const float*)d_in[6];
  const float* ee2 = (const float*)d_in[7];
  const float* W1  = (const float*)d_in[8];
  const float* b1  = (const float*)d_in[9];
  const float* W2  = (const float*)d_in[10];
  const float* b2  = (const float*)d_in[11];
  const float* gamma = (const float*)d_in[12];
  const float* beta  = (const float*)d_in[13];
  const float* mean  = (const float*)d_in[14];
  const float* var   = (const float*)d_in[15];
  const float* pa    = (const float*)d_in[16];
  const float* n2dW  = (const float*)d_in[17];
  const float* de1   = (const float*)d_in[18];
  const float* de2   = (const float*)d_in[19];
  const float* dW1   = (const float*)d_in[20];
  const float* db1   = (const float*)d_in[21];
  const float* dW2   = (const float*)d_in[22];
  const float* db2   = (const float*)d_in[23];

  // ---- preprocessing ----
  hipMemsetAsync(flag, 0, 4, stream);
  hipMemsetAsync(cur, 0, (size_t)N * 4, stream);
  k_detect<<<256, 256, 0, stream>>>((const unsigned int*)mraw, N / 4, flag);
  k_norm<<<(N + 255) / 256, 256, 0, stream>>>(mraw, flag, mask, N);
  k_count<<<2048, 256, 0, stream>>>(ei, E, cur);
  const int nchunks = (N + 1023) / 1024;
  k_scanA<<<nchunks, 1024, 0, stream>>>(cur, offv, bsum, N);
  k_scanB<<<1, 64, 0, stream>>>(bsum, offv + N, nchunks);
  k_scanC<<<(N + 255) / 256, 256, 0, stream>>>(offv, bsum, N);
  hipMemcpyAsync(cur, offv, (size_t)N * 4, hipMemcpyDeviceToDevice, stream);
  k_fill<<<2048, 256, 0, stream>>>(ei, ea, E, cur, elist);
  k_counts<<<(N + 255) / 256, 256, 0, stream>>>(offv, elist, cnts, N);
  k_tab<<<(54 * 512 + 255) / 256, 256, 0, stream>>>(ee1, ee2, de1, de2, tab);

  k_conv_w<<<2048, 256, 0, stream>>>(W1, w1H, 500, 1000, 512, 1024, 5);
  k_conv_w<<<2048, 256, 0, stream>>>(W2, w2H, 1000, 500, 1024, 512, 5);
  k_conv_w<<<1024, 256, 0, stream>>>(n2dW, ndH, 500, 500, 512, 512, 1);
  k_conv_w<<<1024, 256, 0, stream>>>(dW1, d1H, 500, 1000, 512, 1024, 1);
  k_conv_w<<<1024, 256, 0, stream>>>(dW2, d2H, 1000, 119, 1024, 128, 1);
  k_init_h<<<4096, 256, 0, stream>>>(x, ae1, ae2, h, N);

  const int aggGrid = (N + 7) / 8;
  EpiParams P{};

  // ---- encoder ----
  for (int l = 0; l < 5; ++l) {
    k_aggregate<<<aggGrid, 256, 0, stream>>>(h, offv, elist, cnts,
                                             tab + (size_t)l * 9 * 512, agg, N);
    P = EpiParams{};
    P.bias = b1 + (size_t)l * 1000;
    P.outH = tmp; P.ldOut = 1024; P.nReal = 1000; P.mReal = Mpad; P.relu = 1;
    k_gemm<EPI_TMP><<<MT * 8, 256, 0, stream>>>(
        agg, w1H + (size_t)l * 1024 * 512, 512, 512, 8, MT * 8, P);

    P = EpiParams{};
    P.bias = b2 + (size_t)l * 500;
    P.mean = mean + (size_t)l * 500; P.var = var + (size_t)l * 500;
    P.gamma = gamma + (size_t)l * 500; P.beta = beta + (size_t)l * 500;
    if (l < 4) {
      P.outH = h; P.ldOut = 512; P.nReal = 500; P.mReal = Mpad; P.relu = 1;
      k_gemm<EPI_BN><<<MT * 4, 256, 0, stream>>>(
          tmp, w2H + (size_t)l * 512 * 1024, 1024, 1024, 4, MT * 4, P);
    } else {
      // fused BN (no relu) + PReLU -> writes n2d A-operand directly
      P.pa = pa;
      P.outH = agg; P.ldOut = 512; P.nReal = 500; P.mReal = Mpad; P.relu = 0;
      k_gemm<EPI_BNPRELU><<<MT * 4, 256, 0, stream>>>(
          tmp, w2H + (size_t)l * 512 * 1024, 1024, 1024, 4, MT * 4, P);
    }
  }

  // ---- encoder_to_decoder: linear(no bias) + mask ----
  P = EpiParams{};
  P.outH = h; P.mask = mask; P.ldOut = 512; P.nReal = 500; P.mReal = N;
  k_gemm<EPI_N2D><<<MT * 4, 256, 0, stream>>>(agg, ndH, 512, 512, 4, MT * 4, P);

  // ---- decoder GIN ----
  k_aggregate<<<aggGrid, 256, 0, stream>>>(h, offv, elist, cnts,
                                           tab + (size_t)5 * 9 * 512, agg, N);
  P = EpiParams{};
  P.bias = db1; P.outH = tmp; P.ldOut = 1024; P.nReal = 1000; P.mReal = Mpad; P.relu = 1;
  k_gemm<EPI_TMP><<<MT * 8, 256, 0, stream>>>(agg, d1H, 512, 512, 8, MT * 8, P);

  P = EpiParams{};
  P.bias = db2; P.outF = (float*)d_out; P.ldOut = 119; P.nReal = 119; P.mReal = N;
  k_gemm<EPI_OUT><<<MT * 1, 256, 0, stream>>>(tmp, d2H, 1024, 1024, 1, MT, P);
}

// Round 9
// 1358.482 us; speedup vs baseline: 1.0597x; 1.0597x over previous
//
#include <hip/hip_runtime.h>
#include <stdint.h>

// ===================== types & helpers =====================
typedef unsigned short u16;
typedef __bf16 bf16x8 __attribute__((ext_vector_type(8)));
typedef float f32x4 __attribute__((ext_vector_type(4)));

enum { EPI_TMP = 0, EPI_BN = 1, EPI_N2D = 2, EPI_OUT = 3, EPI_BNPRELU = 4 };

__device__ __forceinline__ u16 f2bf(float x) {
  unsigned int u = __float_as_uint(x);
  u += 0x7FFFu + ((u >> 16) & 1u);           // RNE
  return (u16)(u >> 16);
}
__device__ __forceinline__ float bf2f(u16 b) {
  return __uint_as_float(((unsigned int)b) << 16);
}
__device__ __forceinline__ float bflo(unsigned int u) { return __uint_as_float(u << 16); }
__device__ __forceinline__ float bfhi(unsigned int u) { return __uint_as_float(u & 0xFFFF0000u); }
__device__ __forceinline__ ushort4 pack4(float a, float b, float c, float d) {
  return make_ushort4(f2bf(a), f2bf(b), f2bf(c), f2bf(d));
}

struct F4 { float x, y, z, w; };
__device__ __forceinline__ F4 ld4(const float* p) {
  float4 v = *(const float4*)p;
  return {v.x, v.y, v.z, v.w};
}

typedef const void __attribute__((address_space(1))) as1cv;
typedef void __attribute__((address_space(3))) as3v;
__device__ __forceinline__ void gld16(const void* g, void* l) {
  __builtin_amdgcn_global_load_lds((as1cv*)g, (as3v*)l, 16, 0, 0);
}

// ===================== preprocessing kernels =====================

__global__ void k_detect(const unsigned int* __restrict__ m, int nwords, int* __restrict__ flag) {
  int viol = 0;
  for (int i = blockIdx.x * blockDim.x + threadIdx.x; i < nwords; i += gridDim.x * blockDim.x) {
    unsigned int u = m[i];
    if (u > 1u) viol |= 1;
    if (u != 0u && u != 0x3F800000u) viol |= 2;
  }
  if (viol) atomicOr(flag, viol);
}

__global__ void k_norm(const void* __restrict__ raw, const int* __restrict__ flag,
                       unsigned char* __restrict__ mout, int N) {
  int f = *flag;
  for (int v = blockIdx.x * blockDim.x + threadIdx.x; v < N; v += gridDim.x * blockDim.x) {
    unsigned char b;
    if ((f & 1) == 0)       b = (unsigned char)(((const int*)raw)[v] != 0);
    else if ((f & 2) == 0)  b = (unsigned char)(((const float*)raw)[v] != 0.0f);
    else                    b = (unsigned char)(((const unsigned char*)raw)[v] != 0);
    mout[v] = b;
  }
}

__global__ void k_count(const int* __restrict__ ei, int E, int* __restrict__ deg) {
  for (int e = blockIdx.x * blockDim.x + threadIdx.x; e < E; e += gridDim.x * blockDim.x)
    atomicAdd(&deg[ei[E + e]], 1);
}

__global__ __launch_bounds__(1024)
void k_scanA(const int* __restrict__ deg, int* __restrict__ out,
             int* __restrict__ bsum, int n) {
  __shared__ int lws[17];
  const int tid = threadIdx.x, lane = tid & 63, wv = tid >> 6;
  const int i = blockIdx.x * 1024 + tid;
  const int v = (i < n) ? deg[i] : 0;
  int x = v;
#pragma unroll
  for (int d = 1; d < 64; d <<= 1) {
    int y = __shfl_up(x, d, 64);
    if (lane >= d) x += y;
  }
  if (lane == 63) lws[wv] = x;
  __syncthreads();
  if (tid == 0) {
    int run = 0;
#pragma unroll
    for (int k = 0; k < 16; ++k) { int t = lws[k]; lws[k] = run; run += t; }
    lws[16] = run;
  }
  __syncthreads();
  if (i < n) out[i] = x - v + lws[wv];
  if (tid == 0) bsum[blockIdx.x] = lws[16];
}

__global__ void k_scanB(int* __restrict__ bsum, int* __restrict__ offN, int nc) {
  const int t = threadIdx.x;          // 64 threads
  const int v = (t < nc) ? bsum[t] : 0;
  int x = v;
#pragma unroll
  for (int d = 1; d < 64; d <<= 1) {
    int y = __shfl_up(x, d, 64);
    if (t >= d) x += y;
  }
  if (t < nc) bsum[t] = x - v;
  if (t == nc - 1) *offN = x;
}

__global__ void k_scanC(int* __restrict__ off_, const int* __restrict__ bsum, int n) {
  int i = blockIdx.x * blockDim.x + threadIdx.x;
  if (i < n) off_[i] += bsum[i >> 10];
}

__global__ void k_fill(const int* __restrict__ ei, const int* __restrict__ ea, int E,
                       int* __restrict__ cur, int* __restrict__ elist) {
  for (int e = blockIdx.x * blockDim.x + threadIdx.x; e < E; e += gridDim.x * blockDim.x) {
    int s = ei[e];
    int d = ei[E + e];
    int a0 = ea[2 * e], a1 = ea[2 * e + 1];
    int pos = atomicAdd(&cur[d], 1);
    elist[pos] = s | (a0 << 20) | (a1 << 23);
  }
}

__global__ void k_counts(const int* __restrict__ off_, const int* __restrict__ elist,
                         unsigned char* __restrict__ cnts, int N) {
  int v = blockIdx.x * blockDim.x + threadIdx.x;
  if (v >= N) return;
  int c0=0,c1=0,c2=0,c3=0,c4=0,c5=0,d0=0,d1=0,d2=0;
  const int e1 = off_[v + 1];
  for (int e = off_[v]; e < e1; ++e) {
    int p = elist[e];
    int a = (p >> 20) & 7, b = (p >> 23) & 3;
    c0 += (a==0); c1 += (a==1); c2 += (a==2);
    c3 += (a==3); c4 += (a==4); c5 += (a==5);
    d0 += (b==0); d1 += (b==1); d2 += (b==2);
  }
  unsigned char* cp = cnts + v * 12;
  cp[0]=(unsigned char)c0; cp[1]=(unsigned char)c1; cp[2]=(unsigned char)c2;
  cp[3]=(unsigned char)c3; cp[4]=(unsigned char)c4; cp[5]=(unsigned char)c5;
  cp[6]=(unsigned char)d0; cp[7]=(unsigned char)d1; cp[8]=(unsigned char)d2;
}

// edge-emb tables -> padded [6 slots][9 rows][512], zeros in pad cols
__global__ void k_tab(const float* __restrict__ ee1, const float* __restrict__ ee2,
                      const float* __restrict__ de1, const float* __restrict__ de2,
                      float* __restrict__ tab) {
  int idx = blockIdx.x * blockDim.x + threadIdx.x;
  if (idx >= 54 * 512) return;
  int col = idx & 511, row = (idx >> 9) % 9, l = idx / (9 * 512);
  float v = 0.f;
  if (col < 500) {
    if (l < 5) v = (row < 6) ? ee1[((size_t)l * 6 + row) * 500 + col]
                             : ee2[((size_t)l * 3 + (row - 6)) * 500 + col];
    else       v = (row < 6) ? de1[(size_t)row * 500 + col]
                             : de2[(size_t)(row - 6) * 500 + col];
  }
  tab[idx] = v;
}

// weights: fp32 [L][K][Nsrc] -> bf16 transposed+padded [L][Npad][Kpad]
__global__ void k_conv_w(const float* __restrict__ src, u16* __restrict__ dst,
                         int K, int Nsrc, int Kpad, int Npad, int L) {
  size_t total = (size_t)L * Npad * Kpad;
  for (size_t idx = blockIdx.x * (size_t)blockDim.x + threadIdx.x; idx < total;
       idx += (size_t)gridDim.x * blockDim.x) {
    int k = (int)(idx % (size_t)Kpad);
    size_t r = idx / (size_t)Kpad;
    int n = (int)(r % (size_t)Npad);
    int l = (int)(r / (size_t)Npad);
    float v = 0.0f;
    if (k < K && n < Nsrc) v = src[((size_t)l * K + k) * Nsrc + n];
    dst[idx] = f2bf(v);
  }
}

// h stride = 512 u16 (1KB aligned rows); pad cols zeroed
__global__ void k_init_h(const int* __restrict__ x, const float* __restrict__ e1,
                         const float* __restrict__ e2, u16* __restrict__ h, int nReal) {
  int total = nReal * 128;
  for (int i = blockIdx.x * blockDim.x + threadIdx.x; i < total; i += gridDim.x * blockDim.x) {
    int v = i >> 7, q = i & 127, j = q << 2;
    u16* hp = h + ((size_t)v << 9) + j;
    if (j < 500) {
      int a = x[2 * v], c = x[2 * v + 1];
      F4 va = ld4(e1 + (size_t)a * 500 + j);
      F4 vc = ld4(e2 + (size_t)c * 500 + j);
      *(ushort4*)hp = pack4(va.x + vc.x, va.y + vc.y, va.z + vc.z, va.w + vc.w);
    } else {
      *(ushort4*)hp = make_ushort4(0, 0, 0, 0);
    }
  }
}

// ===================== aggregation: 1 wave/node, 8-deep gather pipeline =====================
// __launch_bounds__(256, 6): VGPR cap ~85 so the 8 uint4 gathers stay genuinely in
// flight (R7 compiled to VGPR=32 -> serialized). Trades 8 -> 6 waves/SIMD for 4x ILP.
__device__ __forceinline__ void add8(float* s, uint4 u) {
  s[0] += bflo(u.x); s[1] += bfhi(u.x);
  s[2] += bflo(u.y); s[3] += bfhi(u.y);
  s[4] += bflo(u.z); s[5] += bfhi(u.z);
  s[6] += bflo(u.w); s[7] += bfhi(u.w);
}

__global__ __launch_bounds__(256, 6)
void k_aggregate(const u16* __restrict__ h, const int* __restrict__ off_,
                 const int* __restrict__ elist, const unsigned char* __restrict__ cnts,
                 const float* __restrict__ tab, u16* __restrict__ agg, int nReal) {
  const int lane = threadIdx.x & 63, wv = threadIdx.x >> 6;
  const int v = (blockIdx.x << 2) | wv;
  if (v >= nReal) return;
  const int j = lane << 3;                    // 8 bf16 per lane; pad cols are zero
  float s[8];
  {
    uint4 u = *(const uint4*)(h + ((size_t)v << 9) + j);   // self-loop h term
    s[0] = bflo(u.x); s[1] = bfhi(u.x); s[2] = bflo(u.y); s[3] = bfhi(u.y);
    s[4] = bflo(u.z); s[5] = bfhi(u.z); s[6] = bflo(u.w); s[7] = bfhi(u.w);
  }
  const int eE = off_[v + 1];
  int e = off_[v];
  for (; e + 8 <= eE; e += 8) {               // 8 gather loads in flight
    const int p0 = elist[e]     & 0xFFFFF, p1 = elist[e + 1] & 0xFFFFF;
    const int p2 = elist[e + 2] & 0xFFFFF, p3 = elist[e + 3] & 0xFFFFF;
    const int p4 = elist[e + 4] & 0xFFFFF, p5 = elist[e + 5] & 0xFFFFF;
    const int p6 = elist[e + 6] & 0xFFFFF, p7 = elist[e + 7] & 0xFFFFF;
    uint4 u0 = *(const uint4*)(h + ((size_t)p0 << 9) + j);
    uint4 u1 = *(const uint4*)(h + ((size_t)p1 << 9) + j);
    uint4 u2 = *(const uint4*)(h + ((size_t)p2 << 9) + j);
    uint4 u3 = *(const uint4*)(h + ((size_t)p3 << 9) + j);
    uint4 u4 = *(const uint4*)(h + ((size_t)p4 << 9) + j);
    uint4 u5 = *(const uint4*)(h + ((size_t)p5 << 9) + j);
    uint4 u6 = *(const uint4*)(h + ((size_t)p6 << 9) + j);
    uint4 u7 = *(const uint4*)(h + ((size_t)p7 << 9) + j);
    add8(s, u0); add8(s, u1); add8(s, u2); add8(s, u3);
    add8(s, u4); add8(s, u5); add8(s, u6); add8(s, u7);
  }
  for (; e + 4 <= eE; e += 4) {
    uint4 u0 = *(const uint4*)(h + ((size_t)(elist[e]     & 0xFFFFF) << 9) + j);
    uint4 u1 = *(const uint4*)(h + ((size_t)(elist[e + 1] & 0xFFFFF) << 9) + j);
    uint4 u2 = *(const uint4*)(h + ((size_t)(elist[e + 2] & 0xFFFFF) << 9) + j);
    uint4 u3 = *(const uint4*)(h + ((size_t)(elist[e + 3] & 0xFFFFF) << 9) + j);
    add8(s, u0); add8(s, u1); add8(s, u2); add8(s, u3);
  }
  for (; e < eE; ++e) {
    uint4 u = *(const uint4*)(h + ((size_t)(elist[e] & 0xFFFFF) << 9) + j);
    add8(s, u);
  }
  // hoisted edge-emb: counts x table rows (+1 on t1[4], t2[0] for self loop)
  const unsigned char* cp = cnts + v * 12;
  constexpr float ex[9] = {0.f,0.f,0.f,0.f,1.f,0.f, 1.f,0.f,0.f};
#pragma unroll
  for (int k = 0; k < 9; ++k) {
    const float ck = (float)cp[k] + ex[k];
    F4 t0 = ld4(tab + (k << 9) + j);
    F4 t1 = ld4(tab + (k << 9) + j + 4);
    s[0] += ck * t0.x; s[1] += ck * t0.y; s[2] += ck * t0.z; s[3] += ck * t0.w;
    s[4] += ck * t1.x; s[5] += ck * t1.y; s[6] += ck * t1.z; s[7] += ck * t1.w;
  }
  auto pk = [](float a, float b) {
    return (unsigned int)f2bf(a) | ((unsigned int)f2bf(b) << 16);
  };
  uint4 o = {pk(s[0], s[1]), pk(s[2], s[3]), pk(s[4], s[5]), pk(s[6], s[7])};
  *(uint4*)(agg + ((size_t)v << 9) + j) = o;
}

// ===================== GEMM: m97 structure (128x128, BK=64, 3 blocks/CU) + LDS-staged epilogue ======
// PROVEN R6 config (1377us, absmax 0.0098). Do not touch the sync structure.
struct EpiParams {
  const float* bias;
  const float* mean; const float* var; const float* gamma; const float* beta;
  const unsigned char* mask;
  const float* pa;
  float* outF;
  u16* outH;
  int ldOut, nReal, mReal, relu;
};

#define EPI_STRIDE 136   // u16; 272B rows, 16B-aligned

template<int EPI>
__global__ __launch_bounds__(256, 3)
void k_gemm(const u16* __restrict__ A, const u16* __restrict__ B,
            int ldA, int Kpad, int Ntiles, int NWG, EpiParams P) {
  // mainloop: sA = smem[0..8192), sB = smem[8192..16384)  (32KB)
  // epilogue: u16 tile 128 x EPI_STRIDE = 34816B  (or f32 64x132 two-pass)
  __shared__ __align__(16) u16 smem[128 * EPI_STRIDE];

  const int tid = threadIdx.x;
  const int w = tid >> 6, lane = tid & 63;
  // bijective XCD swizzle: consecutive wgs (same A-panel) cluster per XCD L2
  const int q = NWG >> 3, r = NWG & 7;
  const int xcd = blockIdx.x & 7, ii = blockIdx.x >> 3;
  const int wg = (xcd < r ? xcd * (q + 1) : r * (q + 1) + (xcd - r) * q) + ii;
  const int mt = wg / Ntiles, nt = wg % Ntiles;
  const int wm = w >> 1, wn = w & 1;          // 2x2 waves, wave tile 64x64

  f32x4 acc[4][4] = {};
  const size_t arow = (size_t)mt * 128, brow = (size_t)nt * 128;
  const int Ksteps = Kpad >> 6;

  for (int ks = 0; ks < Ksteps; ++ks) {
    const int kb = ks << 6;
#pragma unroll
    for (int it = 0; it < 4; ++it) {
      const int idx = (it << 8) | tid;
      const int row = idx >> 3, s = idx & 7;
      const int col = kb + ((s ^ (row & 7)) << 3);   // inverse-swizzled SOURCE col
      u16* dst = smem + (((it << 8) | (w << 6)) << 3);  // wave-uniform LDS base
      gld16(A + (arow + row) * (size_t)ldA + col, dst);
      gld16(B + (brow + row) * (size_t)Kpad + col, dst + 8192);
    }
    asm volatile("s_waitcnt vmcnt(0)" ::: "memory");
    __syncthreads();

#pragma unroll
    for (int kk = 0; kk < 2; ++kk) {
      const int ko8 = (kk << 2) | (lane >> 4);
      const int sw = (ko8 ^ (lane & 7)) << 3;        // swizzled read
      bf16x8 af[4], bfr[4];
#pragma unroll
      for (int m = 0; m < 4; ++m)
        af[m] = *(const bf16x8*)(smem + ((((wm << 6) | (m << 4) | (lane & 15))) << 6) + sw);
#pragma unroll
      for (int n = 0; n < 4; ++n)
        bfr[n] = *(const bf16x8*)(smem + 8192 + ((((wn << 6) | (n << 4) | (lane & 15))) << 6) + sw);
#pragma unroll
      for (int m = 0; m < 4; ++m)
#pragma unroll
        for (int n = 0; n < 4; ++n)
          acc[m][n] = __builtin_amdgcn_mfma_f32_16x16x32_bf16(af[m], bfr[n], acc[m][n], 0, 0, 0);
    }
    __syncthreads();
  }

  // ---- epilogue; C/D map: col = lane&15, row = (lane>>4)*4 + reg ----
  const int rb0 = mt * 128, cb0 = nt * 128;
  const int rloc = (wm << 6) | ((lane >> 4) << 2);   // + (m<<4) + r
  const int cloc = (wn << 6) | (lane & 15);          // + (n<<4)

  if constexpr (EPI != EPI_OUT) {
    float alpha = 0.f;
    if constexpr (EPI == EPI_BNPRELU) alpha = *P.pa;
    // per-element math in-register -> bf16 tile in LDS -> coalesced uint4 stores
#pragma unroll
    for (int n = 0; n < 4; ++n) {
      const int col = cloc + (n << 4);
      const int colg = cb0 + col;
      const bool cok = colg < P.nReal;
      float bias = 0.f, bnS = 0.f, bnB = 0.f;
      if constexpr (EPI == EPI_TMP) {
        if (cok) bias = P.bias[colg];
      }
      if constexpr (EPI == EPI_BN || EPI == EPI_BNPRELU) {
        if (cok) {
          bias = P.bias[colg];
          bnS = rsqrtf(P.var[colg] + 1e-5f) * P.gamma[colg];
          bnB = P.beta[colg] - P.mean[colg] * bnS;
        }
      }
#pragma unroll
      for (int m = 0; m < 4; ++m) {
#pragma unroll
        for (int rr = 0; rr < 4; ++rr) {
          const int row = rloc + (m << 4) + rr;
          float z = acc[m][n][rr];
          if constexpr (EPI == EPI_TMP) {
            z = fmaxf(z + bias, 0.f);
          } else if constexpr (EPI == EPI_BN) {
            z = (z + bias) * bnS + bnB;
            if (P.relu) z = fmaxf(z, 0.f);
          } else if constexpr (EPI == EPI_BNPRELU) {
            z = (z + bias) * bnS + bnB;
            z = z >= 0.f ? z : alpha * z;
          } else {  // EPI_N2D
            const int rowg = rb0 + row;
            if (rowg < P.mReal && P.mask[rowg]) z = 0.f;
          }
          smem[row * EPI_STRIDE + col] = f2bf(z);
        }
      }
    }
    __syncthreads();
#pragma unroll
    for (int it = 0; it < 8; ++it) {
      const int idx = (it << 8) | tid;
      const int row = idx >> 4, c8 = idx & 15;
      uint4 vv = *(const uint4*)(smem + row * EPI_STRIDE + (c8 << 3));
      *(uint4*)(P.outH + (size_t)(rb0 + row) * P.ldOut + cb0 + (c8 << 3)) = vv;
    }
  } else {
    // f32 output, ld=119 exact: two-pass LDS stage + flat contiguous stores
    float* sf = (float*)smem;                        // 64 x 132 f32 = 33792B
#pragma unroll
    for (int p = 0; p < 2; ++p) {
      __syncthreads();
      if (wm == p) {
#pragma unroll
        for (int n = 0; n < 4; ++n) {
          const int col = cloc + (n << 4);
          const float bias = (cb0 + col < P.nReal) ? P.bias[cb0 + col] : 0.f;
#pragma unroll
          for (int m = 0; m < 4; ++m)
#pragma unroll
            for (int rr = 0; rr < 4; ++rr) {
              const int lrow = ((lane >> 4) << 2) + (m << 4) + rr;   // 0..63
              sf[lrow * 132 + col] = acc[m][n][rr] + bias;
            }
        }
      }
      __syncthreads();
      const size_t flat0 = (size_t)(rb0 + (p << 6)) * 119;
      const size_t flatEnd = (size_t)P.mReal * 119;
#pragma unroll 2
      for (int it = 0; it < 30; ++it) {
        const int fidx = it * 256 + tid;
        if (fidx < 64 * 119) {
          const int row = fidx / 119;
          const int col = fidx - row * 119;
          const size_t g = flat0 + fidx;
          if (g < flatEnd) P.outF[g] = sf[row * 132 + col];
        }
      }
    }
  }
}

__global__ void k_fail(float* out, int n, float val) {
  for (int i = blockIdx.x * blockDim.x + threadIdx.x; i < n; i += gridDim.x * blockDim.x)
    out[i] = (i == 0) ? val : 0.f;
}

// ===================== host side =====================
static inline size_t alup(size_t x) { return (x + 255) & ~(size_t)255; }

extern "C" void kernel_launch(void* const* d_in, const int* in_sizes, int n_in,
                              void* d_out, int out_size, void* d_ws, size_t ws_size,
                              hipStream_t stream) {
  (void)n_in;
  const int N = in_sizes[0] / 2;
  const int E = in_sizes[1] / 2;
  const int Mpad = (N + 127) / 128 * 128;
  const int MT = Mpad / 128;

  // ---- plan ----
  size_t off = 0;
  auto plan = [&](size_t b) -> size_t { size_t p = off; off += alup(b); return p; };
  const size_t o_h    = plan((size_t)Mpad * 512 * 2);
  const size_t o_agg  = plan((size_t)Mpad * 512 * 2);
  const size_t o_tmp  = plan((size_t)Mpad * 1024 * 2);
  const size_t o_w1   = plan(5ull * 1024 * 512 * 2);
  const size_t o_w2   = plan(5ull * 512 * 1024 * 2);
  const size_t o_nd   = plan(512ull * 512 * 2);
  const size_t o_d1   = plan(1024ull * 512 * 2);
  const size_t o_d2   = plan(128ull * 1024 * 2);
  const size_t o_tab  = plan(54ull * 512 * 4);
  const size_t o_offv = plan((size_t)(N + 1) * 4);
  const size_t o_cur  = plan((size_t)N * 4);
  const size_t o_el   = plan((size_t)E * 4);
  const size_t o_mask = plan((size_t)N);
  const size_t o_cnt  = plan((size_t)N * 12);
  const size_t o_bsum = plan(1024);
  const size_t o_flag = plan(256);
  const size_t need = off;

  if (ws_size < need) {
    k_fail<<<1024, 256, 0, stream>>>((float*)d_out, out_size, -(float)(ws_size >> 20));
    return;
  }

  char* ws = (char*)d_ws;
  u16* h     = (u16*)(ws + o_h);
  u16* agg   = (u16*)(ws + o_agg);
  u16* tmp   = (u16*)(ws + o_tmp);
  u16* w1H   = (u16*)(ws + o_w1);
  u16* w2H   = (u16*)(ws + o_w2);
  u16* ndH   = (u16*)(ws + o_nd);
  u16* d1H   = (u16*)(ws + o_d1);
  u16* d2H   = (u16*)(ws + o_d2);
  float* tab = (float*)(ws + o_tab);
  int* offv  = (int*)(ws + o_offv);
  int* cur   = (int*)(ws + o_cur);
  int* elist = (int*)(ws + o_el);
  unsigned char* mask = (unsigned char*)(ws + o_mask);
  unsigned char* cnts = (unsigned char*)(ws + o_cnt);
  int* bsum  = (int*)(ws + o_bsum);
  int* flag  = (int*)(ws + o_flag);

  const int* x   = (const int*)d_in[0];
  const int* ei  = (const int*)d_in[1];
  const int* ea  = (const int*)d_in[2];
  const void* mraw = d_in[3];
  const float* ae1 = (const float*)d_in[4];
  const float* ae2 = (const float*)d_in[5];
  const float* ee1 = (const float*)d_in[6];
  const float* ee2 = (const float*)d_in[7];
  const float* W1  = (const float*)d_in[8];
  const float* b1  = (const float*)d_in[9];
  const float* W2  = (const float*)d_in[10];
  const float* b2  = (const float*)d_in[11];
  const float* gamma = (const float*)d_in[12];
  const float* beta  = (const float*)d_in[13];
  const float* mean  = (const float*)d_in[14];
  const float* var   = (const float*)d_in[15];
  const float* pa    = (const float*)d_in[16];
  const float* n2dW  = (const float*)d_in[17];
  const float* de1   = (const float*)d_in[18];
  const float* de2   = (const float*)d_in[19];
  const float* dW1   = (const float*)d_in[20];
  const float* db1   = (const float*)d_in[21];
  const float* dW2   = (const float*)d_in[22];
  const float* db2   = (const float*)d_in[23];

  // ---- preprocessing ----
  hipMemsetAsync(flag, 0, 4, stream);
  hipMemsetAsync(cur, 0, (size_t)N * 4, stream);
  k_detect<<<256, 256, 0, stream>>>((const unsigned int*)mraw, N / 4, flag);
  k_norm<<<(N + 255) / 256, 256, 0, stream>>>(mraw, flag, mask, N);
  k_count<<<2048, 256, 0, stream>>>(ei, E, cur);
  const int nchunks = (N + 1023) / 1024;
  k_scanA<<<nchunks, 1024, 0, stream>>>(cur, offv, bsum, N);
  k_scanB<<<1, 64, 0, stream>>>(bsum, offv + N, nchunks);
  k_scanC<<<(N + 255) / 256, 256, 0, stream>>>(offv, bsum, N);
  hipMemcpyAsync(cur, offv, (size_t)N * 4, hipMemcpyDeviceToDevice, stream);
  k_fill<<<2048, 256, 0, stream>>>(ei, ea, E, cur, elist);
  k_counts<<<(N + 255) / 256, 256, 0, stream>>>(offv, elist, cnts, N);
  k_tab<<<(54 * 512 + 255) / 256, 256, 0, stream>>>(ee1, ee2, de1, de2, tab);

  k_conv_w<<<2048, 256, 0, stream>>>(W1, w1H, 500, 1000, 512, 1024, 5);
  k_conv_w<<<2048, 256, 0, stream>>>(W2, w2H, 1000, 500, 1024, 512, 5);
  k_conv_w<<<1024, 256, 0, stream>>>(n2dW, ndH, 500, 500, 512, 512, 1);
  k_conv_w<<<1024, 256, 0, stream>>>(dW1, d1H, 500, 1000, 512, 1024, 1);
  k_conv_w<<<1024, 256, 0, stream>>>(dW2, d2H, 1000, 119, 1024, 128, 1);
  k_init_h<<<4096, 256, 0, stream>>>(x, ae1, ae2, h, N);

  const int aggGrid = (N + 3) / 4;
  EpiParams P{};

  // ---- encoder ----
  for (int l = 0; l < 5; ++l) {
    k_aggregate<<<aggGrid, 256, 0, stream>>>(h, offv, elist, cnts,
                                             tab + (size_t)l * 9 * 512, agg, N);
    P = EpiParams{};
    P.bias = b1 + (size_t)l * 1000;
    P.outH = tmp; P.ldOut = 1024; P.nReal = 1000; P.mReal = Mpad; P.relu = 1;
    k_gemm<EPI_TMP><<<MT * 8, 256, 0, stream>>>(
        agg, w1H + (size_t)l * 1024 * 512, 512, 512, 8, MT * 8, P);

    P = EpiParams{};
    P.bias = b2 + (size_t)l * 500;
    P.mean = mean + (size_t)l * 500; P.var = var + (size_t)l * 500;
    P.gamma = gamma + (size_t)l * 500; P.beta = beta + (size_t)l * 500;
    if (l < 4) {
      P.outH = h; P.ldOut = 512; P.nReal = 500; P.mReal = Mpad; P.relu = 1;
      k_gemm<EPI_BN><<<MT * 4, 256, 0, stream>>>(
          tmp, w2H + (size_t)l * 512 * 1024, 1024, 1024, 4, MT * 4, P);
    } else {
      // fused BN (no relu) + PReLU -> writes n2d A-operand directly
      P.pa = pa;
      P.outH = agg; P.ldOut = 512; P.nReal = 500; P.mReal = Mpad; P.relu = 0;
      k_gemm<EPI_BNPRELU><<<MT * 4, 256, 0, stream>>>(
          tmp, w2H + (size_t)l * 512 * 1024, 1024, 1024, 4, MT * 4, P);
    }
  }

  // ---- encoder_to_decoder: linear(no bias) + mask ----
  P = EpiParams{};
  P.outH = h; P.mask = mask; P.ldOut = 512; P.nReal = 500; P.mReal = N;
  k_gemm<EPI_N2D><<<MT * 4, 256, 0, stream>>>(agg, ndH, 512, 512, 4, MT * 4, P);

  // ---- decoder GIN ----
  k_aggregate<<<aggGrid, 256, 0, stream>>>(h, offv, elist, cnts,
                                           tab + (size_t)5 * 9 * 512, agg, N);
  P = EpiParams{};
  P.bias = db1; P.outH = tmp; P.ldOut = 1024; P.nReal = 1000; P.mReal = Mpad; P.relu = 1;
  k_gemm<EPI_TMP><<<MT * 8, 256, 0, stream>>>(agg, d1H, 512, 512, 8, MT * 8, P);

  P = EpiParams{};
  P.bias = db2; P.outF = (float*)d_out; P.ldOut = 119; P.nReal = 119; P.mReal = N;
  k_gemm<EPI_OUT><<<MT * 1, 256, 0, stream>>>(tmp, d2H, 1024, 1024, 1, MT, P);
}